// Round 2
// baseline (254.703 us; speedup 1.0000x reference)
//
#include <hip/hip_runtime.h>

// (B,N,DIN,DE,NH,DK) = (4,256,128,64,8,16). Inputs f32, output f32.
#define BB   4
#define NN   256
#define DIN  128
#define DE   64
#define NH   8
#define DK   16
#define CC   128   // NH*DK

typedef __attribute__((ext_vector_type(8))) short short8;   // 8 bf16 = 4 VGPRs
typedef __attribute__((ext_vector_type(4))) float f32x4;

// f32 -> bf16 bits, round-to-nearest-even (round-4-verified numerics)
__device__ __forceinline__ unsigned short f2bfu(float f) {
    union { float f; unsigned int i; } v; v.f = f;
    unsigned int x = v.i;
    x += 0x7FFFu + ((x >> 16) & 1u);
    return (unsigned short)(x >> 16);
}

// ---------------------------------------------------------------------------
// prep: blocks [0,256) do QKV (4 rows per block, verified structure);
//       blocks [256,264) do the one-time WE/WE2 f32->bf16 B-fragment prep.
// wfrag[((m*8+g)*2+ks)*64 + lane] = short8 { W[ks*32+q4*8+ii][g*16+l15] }
// ---------------------------------------------------------------------------
__global__ __launch_bounds__(256) void prep_kernel(
    const float* __restrict__ h, const float* __restrict__ WQ,
    const float* __restrict__ WK, const float* __restrict__ WV,
    const float* __restrict__ WE, const float* __restrict__ WE2,
    float* __restrict__ Qw, float* __restrict__ Kw, float* __restrict__ Vw,
    unsigned short* __restrict__ wfrag)
{
    __shared__ float hsh[4 * DIN];       // 2 KB
    __shared__ float psum[4 * 1536];     // 24 KB
    const int t = threadIdx.x;

    if (blockIdx.x >= 256) {
        // ---- W-frag prep (8 blocks x 256 thr = 2048 threads) ----
        const int tid  = (blockIdx.x - 256) * 256 + t;
        const int m    = tid >> 10;
        const int g    = (tid >> 7) & 7;
        const int ks   = (tid >> 6) & 1;
        const int lane = tid & 63;
        const int q4 = lane >> 4, l15 = lane & 15;
        const float* W = m ? WE2 : WE;
        union { uint4 u; unsigned short s[8]; } pk;
        #pragma unroll
        for (int ii = 0; ii < 8; ++ii) {
            const int d = ks * 32 + q4 * 8 + ii;
            pk.s[ii] = f2bfu(W[d * CC + g * 16 + l15]);
        }
        ((uint4*)wfrag)[tid] = pk.u;
        return;
    }

    // ---- QKV: 4 rows per block ----
    const int r0 = blockIdx.x * 4;
    hsh[t]       = h[(size_t)r0 * DIN + t];
    hsh[256 + t] = h[(size_t)r0 * DIN + 256 + t];
    __syncthreads();

    const int cp  = t & 63;              // channel pair: c = 2cp, 2cp+1
    const int qtr = t >> 6;              // d in [qtr*32, qtr*32+32)
    float aq[4][2], ak[4][2], av[4][2];
    #pragma unroll
    for (int r = 0; r < 4; ++r) {
        aq[r][0]=aq[r][1]=ak[r][0]=ak[r][1]=av[r][0]=av[r][1]=0.f;
    }
    #pragma unroll 4
    for (int dd = 0; dd < 32; ++dd) {
        const int d = qtr * 32 + dd;
        const float2 fq = ((const float2*)WQ)[d * 64 + cp];
        const float2 fk = ((const float2*)WK)[d * 64 + cp];
        const float2 fv = ((const float2*)WV)[d * 64 + cp];
        #pragma unroll
        for (int r = 0; r < 4; ++r) {
            const float hd = hsh[r * DIN + d];
            aq[r][0] = fmaf(hd, fq.x, aq[r][0]); aq[r][1] = fmaf(hd, fq.y, aq[r][1]);
            ak[r][0] = fmaf(hd, fk.x, ak[r][0]); ak[r][1] = fmaf(hd, fk.y, ak[r][1]);
            av[r][0] = fmaf(hd, fv.x, av[r][0]); av[r][1] = fmaf(hd, fv.y, av[r][1]);
        }
    }
    float* pq = psum + qtr * 1536;
    #pragma unroll
    for (int r = 0; r < 4; ++r) {
        pq[r*384       + 2*cp] = aq[r][0]; pq[r*384       + 2*cp+1] = aq[r][1];
        pq[r*384 + 128 + 2*cp] = ak[r][0]; pq[r*384 + 128 + 2*cp+1] = ak[r][1];
        pq[r*384 + 256 + 2*cp] = av[r][0]; pq[r*384 + 256 + 2*cp+1] = av[r][1];
    }
    __syncthreads();
    #pragma unroll
    for (int k = 0; k < 6; ++k) {
        const int o = k * 256 + t;               // 0..1535
        float v = psum[o] + psum[1536 + o] + psum[3072 + o] + psum[4608 + o];
        const int r   = o / 384;
        const int mc  = o - r * 384;
        const int mat = mc >> 7;
        const int c   = mc & 127;
        const size_t idx = (size_t)(r0 + r) * CC + c;
        if      (mat == 0) Qw[idx] = v;
        else if (mat == 1) Kw[idx] = v * 0.25f;  // DK^-0.5
        else               Vw[idx] = v;
    }
}

// ---------------------------------------------------------------------------
// Fused attention, STREAMING version (hand-unrolled pipeline).
// One block (4 waves) per (b,i). e[b,i,:,:] consumed in 8 tiles of 32 rows.
// Depth-2 prefetch lives in NAMED registers x0,x1 / y0,y1 (even/odd tiles);
// the 8-tile loop is macro-expanded so every array index (LDS buffer TT%3,
// prefetch reg, store reg) is a compile-time constant -> no scratch alloca
// (round-1 failure mode: pf[tt&1] runtime index -> 128 MB/dir scratch traffic).
// LDS 22.5 KB, __launch_bounds__(256,4) -> 4 blocks/CU, all 1024 resident.
//
// MFMA 16x16x32 bf16 layouts (HW-verified):
//   A: lane holds A[m=lane&15][k=(lane>>4)*8+ii]
//   B: lane holds B[k=(lane>>4)*8+ii][n=lane&15]
//   C/D: col=lane&15, row=(lane>>4)*4+reg
// ---------------------------------------------------------------------------
__global__ __launch_bounds__(256, 4) void attn_kernel(
    const float* __restrict__ e, const float* __restrict__ maskp,
    const unsigned short* __restrict__ wfrag,
    const float* __restrict__ Qw, const float* __restrict__ Kw,
    const float* __restrict__ Vw, float* __restrict__ out)
{
    __shared__ __align__(16) unsigned short esh[3][32 * DE];  // 12 KB, swizzled
    __shared__ float qk_sh[NN * 9];                           // 9 KB, pad 9
    __shared__ float msk_sh[NN];
    __shared__ float qrow_sh[CC];

    const int row  = blockIdx.x;
    const int b    = row >> 8, i = row & 255;
    const int t    = threadIdx.x;
    const int wave = t >> 6, lane = t & 63;
    const int q4   = lane >> 4;
    const int l15  = lane & 15;

    // staging role: thread t stages row sj_ (0..31) chunk sch (0..7) of a tile
    const int sj_ = t >> 3;
    const int sch = t & 7;
    // per tile: 32 rows x 64 f32 = 512 float4; thread loads a float4 pair
    const float4* esrc = (const float4*)(e + (size_t)row * NN * DE)
                         + (size_t)sj_ * 16 + sch * 2;
    uint4* eshv = (uint4*)esh;   // 768 16B chunks, buffer k at k*256

    // ---- issue tile 0 and tile 1 loads FIRST (HBM critical path) ----
    float4 x0, x1, y0, y1;                 // x: even tiles, y: odd tiles
    x0 = esrc[0];       x1 = esrc[1];      // tile 0
    y0 = esrc[512];     y1 = esrc[512+1];  // tile 1

    // ---- setup while loads fly ----
    if (t < CC) qrow_sh[t] = Qw[(size_t)row * CC + t];
    msk_sh[t] = maskp[b * NN + t];

    short8 bfrag[2][2][2];
    {
        const uint4* wf = (const uint4*)wfrag;
        #pragma unroll
        for (int m = 0; m < 2; ++m)
        #pragma unroll
        for (int ct = 0; ct < 2; ++ct) {
            const int g = wave * 2 + ct;
            #pragma unroll
            for (int ks = 0; ks < 2; ++ks) {
                union { uint4 u; short8 s8; } cv;
                cv.u = wf[((m * 8 + g) * 2 + ks) * 64 + lane];
                bfrag[m][ct][ks] = cv.s8;
            }
        }
    }
    __syncthreads();   // qrow_sh visible

    // ---- qk[j,h], full f32 (thread t = row j) ----
    {
        const float4* kr = (const float4*)(Kw + (size_t)(b * NN + t) * CC);
        #pragma unroll
        for (int hh = 0; hh < NH; ++hh) {
            float s = 0.f;
            #pragma unroll
            for (int p = 0; p < 4; ++p) {
                const float4 kv = kr[hh * 4 + p];
                const int qb = hh * 16 + p * 4;
                s += kv.x * qrow_sh[qb]     + kv.y * qrow_sh[qb + 1]
                   + kv.z * qrow_sh[qb + 2] + kv.w * qrow_sh[qb + 3];
            }
            qk_sh[t * 9 + hh] = s;
        }
    }

#define STORE_TILE(BUF, F0, F1) {                                              \
        union { uint4 u; unsigned short s[8]; } pk;                            \
        pk.s[0]=f2bfu((F0).x); pk.s[1]=f2bfu((F0).y);                          \
        pk.s[2]=f2bfu((F0).z); pk.s[3]=f2bfu((F0).w);                          \
        pk.s[4]=f2bfu((F1).x); pk.s[5]=f2bfu((F1).y);                          \
        pk.s[6]=f2bfu((F1).z); pk.s[7]=f2bfu((F1).w);                          \
        eshv[(BUF)*256 + sj_*8 + (sch ^ (sj_ & 7))] = pk.u; }

    // ---- convert + write tile 0 (waits only on tile-0 loads) ----
    STORE_TILE(0, x0, x1);
    __syncthreads();   // tile 0 + qk_sh visible

    const float mi = msk_sh[i];
    float acc[2] = {0.f, 0.f}, dnm[2] = {0.f, 0.f};

#define COMPUTE_TILE(TT)                                                        \
    {                                                                           \
        const short8* ep = (const short8*)esh[(TT) % 3];                        \
        _Pragma("unroll")                                                       \
        for (int sj = 0; sj < 2; ++sj) {                                        \
            const int rloc = sj * 16 + l15;                                     \
            const short8 a0 = ep[rloc * 8 + ((q4    ) ^ (rloc & 7))];           \
            const short8 a1 = ep[rloc * 8 + ((q4 + 4) ^ (rloc & 7))];           \
            const int jbase = (TT) * 32 + sj * 16;                              \
            _Pragma("unroll")                                                   \
            for (int ct = 0; ct < 2; ++ct) {                                    \
                const int g = wave * 2 + ct;                                    \
                f32x4 s2 = {0.f,0.f,0.f,0.f}, eE = {0.f,0.f,0.f,0.f};           \
                s2 = __builtin_amdgcn_mfma_f32_16x16x32_bf16(a0, bfrag[1][ct][0], s2, 0,0,0); \
                s2 = __builtin_amdgcn_mfma_f32_16x16x32_bf16(a1, bfrag[1][ct][1], s2, 0,0,0); \
                eE = __builtin_amdgcn_mfma_f32_16x16x32_bf16(a0, bfrag[0][ct][0], eE, 0,0,0); \
                eE = __builtin_amdgcn_mfma_f32_16x16x32_bf16(a1, bfrag[0][ct][1], eE, 0,0,0); \
                const float* vrow = Vw + (size_t)(b*NN + jbase + q4*4) * CC + g*16 + l15; \
                _Pragma("unroll")                                               \
                for (int r = 0; r < 4; ++r) {                                   \
                    const int jr = jbase + q4 * 4 + r;                          \
                    float sc = qk_sh[jr * 9 + g] + s2[r];                       \
                    sc = fminf(5.f, fmaxf(-5.f, sc));                           \
                    const float p  = __expf(sc);                                \
                    const float mm = mi * msk_sh[jr];                           \
                    const float s1 = p * mm;               /* mask^1 -> denom */\
                    dnm[ct] += s1;                                              \
                    const float vv = vrow[r * CC];                              \
                    acc[ct] = fmaf(s1 * mm, vv + eE[r], acc[ct]); /* mask^2 */  \
                }                                                               \
            }                                                                   \
        }                                                                       \
    }

    // ITER(TT, load-target regs = tile TT+2, store-source regs = tile TT+1)
#define ITER(TT, L0, L1, S0, S1)                                                \
    {                                                                           \
        if ((TT) < 6) { L0 = esrc[((TT)+2)*512]; L1 = esrc[((TT)+2)*512+1]; }   \
        COMPUTE_TILE(TT);                                                       \
        if ((TT) < 7) { STORE_TILE(((TT)+1) % 3, S0, S1); __syncthreads(); }    \
    }

    ITER(0, x0, x1, y0, y1)   // load t2->x, compute t0, store t1 from y
    ITER(1, y0, y1, x0, x1)   // load t3->y, compute t1, store t2 from x
    ITER(2, x0, x1, y0, y1)
    ITER(3, y0, y1, x0, x1)
    ITER(4, x0, x1, y0, y1)
    ITER(5, y0, y1, x0, x1)
    ITER(6, x0, x1, y0, y1)   // no load, compute t6, store t7 from y
    ITER(7, y0, y1, x0, x1)   // no load, compute t7, no store/sync

#undef ITER
#undef COMPUTE_TILE
#undef STORE_TILE

    // reduce over quad groups (lanes l, l^16, l^32, l^48 share a column)
    #pragma unroll
    for (int ct = 0; ct < 2; ++ct) {
        float a = acc[ct], d = dnm[ct];
        a += __shfl_xor(a, 16); a += __shfl_xor(a, 32);
        d += __shfl_xor(d, 16); d += __shfl_xor(d, 32);
        acc[ct] = a; dnm[ct] = d;
    }
    if (lane < 32) {
        const int ct = lane >> 4;
        out[(size_t)row * CC + wave * 32 + lane] = acc[ct] / fmaxf(dnm[ct], 1e-6f);
    }
}

extern "C" void kernel_launch(void* const* d_in, const int* in_sizes, int n_in,
                              void* d_out, int out_size, void* d_ws, size_t ws_size,
                              hipStream_t stream)
{
    const float* h    = (const float*)d_in[0];
    const float* e    = (const float*)d_in[1];
    const float* mask = (const float*)d_in[2];
    const float* WQ   = (const float*)d_in[3];
    const float* WK   = (const float*)d_in[4];
    const float* WV   = (const float*)d_in[5];
    const float* WE   = (const float*)d_in[6];
    const float* WE2  = (const float*)d_in[7];

    unsigned short* wfrag = (unsigned short*)d_ws;          // 32 KB
    float* Qw = (float*)((char*)d_ws + 32768);              // B*N*C f32 each
    float* Kw = Qw + BB * NN * CC;
    float* Vw = Kw + BB * NN * CC;                          // total ~1.53 MB

    prep_kernel<<<264, 256, 0, stream>>>(h, WQ, WK, WV, WE, WE2,
                                         Qw, Kw, Vw, wfrag);
    attn_kernel<<<BB*NN, 256, 0, stream>>>(e, mask, wfrag, Qw, Kw, Vw,
                                           (float*)d_out);
}

// Round 3
// 147.652 us; speedup vs baseline: 1.7250x; 1.7250x over previous
//
#include <hip/hip_runtime.h>

// (B,N,DIN,DE,NH,DK) = (4,256,128,64,8,16). Inputs f32, output f32.
#define BB   4
#define NN   256
#define DIN  128
#define DE   64
#define NH   8
#define DK   16
#define CC   128   // NH*DK

typedef __attribute__((ext_vector_type(8))) short short8;   // 8 bf16 = 4 VGPRs
typedef __attribute__((ext_vector_type(4))) float f32x4;

// f32 -> bf16 bits, round-to-nearest-even (round-4-verified numerics)
__device__ __forceinline__ unsigned short f2bfu(float f) {
    union { float f; unsigned int i; } v; v.f = f;
    unsigned int x = v.i;
    x += 0x7FFFu + ((x >> 16) & 1u);
    return (unsigned short)(x >> 16);
}

// ---------------------------------------------------------------------------
// prep: blocks [0,256) do QKV (4 rows per block, verified structure);
//       blocks [256,264) do the one-time WE/WE2 f32->bf16 B-fragment prep.
// wfrag[((m*8+g)*2+ks)*64 + lane] = short8 { W[ks*32+q4*8+ii][g*16+l15] }
// ---------------------------------------------------------------------------
__global__ __launch_bounds__(256) void prep_kernel(
    const float* __restrict__ h, const float* __restrict__ WQ,
    const float* __restrict__ WK, const float* __restrict__ WV,
    const float* __restrict__ WE, const float* __restrict__ WE2,
    float* __restrict__ Qw, float* __restrict__ Kw, float* __restrict__ Vw,
    unsigned short* __restrict__ wfrag)
{
    __shared__ float hsh[4 * DIN];       // 2 KB
    __shared__ float psum[4 * 1536];     // 24 KB
    const int t = threadIdx.x;

    if (blockIdx.x >= 256) {
        // ---- W-frag prep (8 blocks x 256 thr = 2048 threads) ----
        const int tid  = (blockIdx.x - 256) * 256 + t;
        const int m    = tid >> 10;
        const int g    = (tid >> 7) & 7;
        const int ks   = (tid >> 6) & 1;
        const int lane = tid & 63;
        const int q4 = lane >> 4, l15 = lane & 15;
        const float* W = m ? WE2 : WE;
        union { uint4 u; unsigned short s[8]; } pk;
        #pragma unroll
        for (int ii = 0; ii < 8; ++ii) {
            const int d = ks * 32 + q4 * 8 + ii;
            pk.s[ii] = f2bfu(W[d * CC + g * 16 + l15]);
        }
        ((uint4*)wfrag)[tid] = pk.u;
        return;
    }

    // ---- QKV: 4 rows per block ----
    const int r0 = blockIdx.x * 4;
    hsh[t]       = h[(size_t)r0 * DIN + t];
    hsh[256 + t] = h[(size_t)r0 * DIN + 256 + t];
    __syncthreads();

    const int cp  = t & 63;              // channel pair: c = 2cp, 2cp+1
    const int qtr = t >> 6;              // d in [qtr*32, qtr*32+32)
    float aq[4][2], ak[4][2], av[4][2];
    #pragma unroll
    for (int r = 0; r < 4; ++r) {
        aq[r][0]=aq[r][1]=ak[r][0]=ak[r][1]=av[r][0]=av[r][1]=0.f;
    }
    #pragma unroll 4
    for (int dd = 0; dd < 32; ++dd) {
        const int d = qtr * 32 + dd;
        const float2 fq = ((const float2*)WQ)[d * 64 + cp];
        const float2 fk = ((const float2*)WK)[d * 64 + cp];
        const float2 fv = ((const float2*)WV)[d * 64 + cp];
        #pragma unroll
        for (int r = 0; r < 4; ++r) {
            const float hd = hsh[r * DIN + d];
            aq[r][0] = fmaf(hd, fq.x, aq[r][0]); aq[r][1] = fmaf(hd, fq.y, aq[r][1]);
            ak[r][0] = fmaf(hd, fk.x, ak[r][0]); ak[r][1] = fmaf(hd, fk.y, ak[r][1]);
            av[r][0] = fmaf(hd, fv.x, av[r][0]); av[r][1] = fmaf(hd, fv.y, av[r][1]);
        }
    }
    float* pq = psum + qtr * 1536;
    #pragma unroll
    for (int r = 0; r < 4; ++r) {
        pq[r*384       + 2*cp] = aq[r][0]; pq[r*384       + 2*cp+1] = aq[r][1];
        pq[r*384 + 128 + 2*cp] = ak[r][0]; pq[r*384 + 128 + 2*cp+1] = ak[r][1];
        pq[r*384 + 256 + 2*cp] = av[r][0]; pq[r*384 + 256 + 2*cp+1] = av[r][1];
    }
    __syncthreads();
    #pragma unroll
    for (int k = 0; k < 6; ++k) {
        const int o = k * 256 + t;               // 0..1535
        float v = psum[o] + psum[1536 + o] + psum[3072 + o] + psum[4608 + o];
        const int r   = o / 384;
        const int mc  = o - r * 384;
        const int mat = mc >> 7;
        const int c   = mc & 127;
        const size_t idx = (size_t)(r0 + r) * CC + c;
        if      (mat == 0) Qw[idx] = v;
        else if (mat == 1) Kw[idx] = v * 0.25f;  // DK^-0.5
        else               Vw[idx] = v;
    }
}

// ---------------------------------------------------------------------------
// Fused attention, STREAMING version (hand-unrolled pipeline).
// One block (4 waves) per (b,i). e[b,i,:,:] consumed in 8 tiles of 32 rows.
// Depth-2 prefetch in named registers x0,x1 / y0,y1; 3-buffer LDS rotation.
//
// __launch_bounds__(256, 3): ROUND-2 POST-MORTEM — (256,4) caps the unified
// VGPR+AGPR file at 128/wave; the pipeline's live state exceeds that, the
// allocator pinned arch-VGPRs at 64 and spilled ~900 B/thread to scratch
// (FETCH/WRITE both ballooned to 236 MB, +120 us). At 3 waves/EU (~170-reg
// cap, same occupancy as the verified 46 us round-0 kernel) nothing spills.
//
// MFMA 16x16x32 bf16 layouts (HW-verified):
//   A: lane holds A[m=lane&15][k=(lane>>4)*8+ii]
//   B: lane holds B[k=(lane>>4)*8+ii][n=lane&15]
//   C/D: col=lane&15, row=(lane>>4)*4+reg
// ---------------------------------------------------------------------------
__global__ __launch_bounds__(256, 3) void attn_kernel(
    const float* __restrict__ e, const float* __restrict__ maskp,
    const unsigned short* __restrict__ wfrag,
    const float* __restrict__ Qw, const float* __restrict__ Kw,
    const float* __restrict__ Vw, float* __restrict__ out)
{
    __shared__ __align__(16) unsigned short esh[3][32 * DE];  // 12 KB, swizzled
    __shared__ float qk_sh[NN * 9];                           // 9 KB, pad 9
    __shared__ float msk_sh[NN];
    __shared__ float qrow_sh[CC];

    const int row  = blockIdx.x;
    const int b    = row >> 8, i = row & 255;
    const int t    = threadIdx.x;
    const int wave = t >> 6, lane = t & 63;
    const int q4   = lane >> 4;
    const int l15  = lane & 15;

    // staging role: thread t stages row sj_ (0..31) chunk sch (0..7) of a tile
    const int sj_ = t >> 3;
    const int sch = t & 7;
    // per tile: 32 rows x 64 f32 = 512 float4; thread loads a float4 pair
    const float4* esrc = (const float4*)(e + (size_t)row * NN * DE)
                         + (size_t)sj_ * 16 + sch * 2;
    uint4* eshv = (uint4*)esh;   // 768 16B chunks, buffer k at k*256

    // ---- issue tile 0 and tile 1 loads FIRST (HBM critical path) ----
    float4 x0, x1, y0, y1;                 // x: even tiles, y: odd tiles
    x0 = esrc[0];       x1 = esrc[1];      // tile 0
    y0 = esrc[512];     y1 = esrc[512+1];  // tile 1

    // ---- setup while loads fly ----
    if (t < CC) qrow_sh[t] = Qw[(size_t)row * CC + t];
    msk_sh[t] = maskp[b * NN + t];

    short8 bfrag[2][2][2];
    {
        const uint4* wf = (const uint4*)wfrag;
        #pragma unroll
        for (int m = 0; m < 2; ++m)
        #pragma unroll
        for (int ct = 0; ct < 2; ++ct) {
            const int g = wave * 2 + ct;
            #pragma unroll
            for (int ks = 0; ks < 2; ++ks) {
                union { uint4 u; short8 s8; } cv;
                cv.u = wf[((m * 8 + g) * 2 + ks) * 64 + lane];
                bfrag[m][ct][ks] = cv.s8;
            }
        }
    }
    __syncthreads();   // qrow_sh visible

    // ---- qk[j,h], full f32 (thread t = row j) ----
    {
        const float4* kr = (const float4*)(Kw + (size_t)(b * NN + t) * CC);
        #pragma unroll
        for (int hh = 0; hh < NH; ++hh) {
            float s = 0.f;
            #pragma unroll
            for (int p = 0; p < 4; ++p) {
                const float4 kv = kr[hh * 4 + p];
                const int qb = hh * 16 + p * 4;
                s += kv.x * qrow_sh[qb]     + kv.y * qrow_sh[qb + 1]
                   + kv.z * qrow_sh[qb + 2] + kv.w * qrow_sh[qb + 3];
            }
            qk_sh[t * 9 + hh] = s;
        }
    }

#define STORE_TILE(BUF, F0, F1) {                                              \
        union { uint4 u; unsigned short s[8]; } pk;                            \
        pk.s[0]=f2bfu((F0).x); pk.s[1]=f2bfu((F0).y);                          \
        pk.s[2]=f2bfu((F0).z); pk.s[3]=f2bfu((F0).w);                          \
        pk.s[4]=f2bfu((F1).x); pk.s[5]=f2bfu((F1).y);                          \
        pk.s[6]=f2bfu((F1).z); pk.s[7]=f2bfu((F1).w);                          \
        eshv[(BUF)*256 + sj_*8 + (sch ^ (sj_ & 7))] = pk.u; }

    // ---- convert + write tile 0 (waits only on tile-0 loads) ----
    STORE_TILE(0, x0, x1);
    __syncthreads();   // tile 0 + qk_sh visible

    const float mi = msk_sh[i];
    float acc[2] = {0.f, 0.f}, dnm[2] = {0.f, 0.f};

#define COMPUTE_TILE(TT)                                                        \
    {                                                                           \
        const short8* ep = (const short8*)esh[(TT) % 3];                        \
        _Pragma("unroll")                                                       \
        for (int sj = 0; sj < 2; ++sj) {                                        \
            const int rloc = sj * 16 + l15;                                     \
            const short8 a0 = ep[rloc * 8 + ((q4    ) ^ (rloc & 7))];           \
            const short8 a1 = ep[rloc * 8 + ((q4 + 4) ^ (rloc & 7))];           \
            const int jbase = (TT) * 32 + sj * 16;                              \
            _Pragma("unroll")                                                   \
            for (int ct = 0; ct < 2; ++ct) {                                    \
                const int g = wave * 2 + ct;                                    \
                f32x4 s2 = {0.f,0.f,0.f,0.f}, eE = {0.f,0.f,0.f,0.f};           \
                s2 = __builtin_amdgcn_mfma_f32_16x16x32_bf16(a0, bfrag[1][ct][0], s2, 0,0,0); \
                s2 = __builtin_amdgcn_mfma_f32_16x16x32_bf16(a1, bfrag[1][ct][1], s2, 0,0,0); \
                eE = __builtin_amdgcn_mfma_f32_16x16x32_bf16(a0, bfrag[0][ct][0], eE, 0,0,0); \
                eE = __builtin_amdgcn_mfma_f32_16x16x32_bf16(a1, bfrag[0][ct][1], eE, 0,0,0); \
                const float* vrow = Vw + (size_t)(b*NN + jbase + q4*4) * CC + g*16 + l15; \
                _Pragma("unroll")                                               \
                for (int r = 0; r < 4; ++r) {                                   \
                    const int jr = jbase + q4 * 4 + r;                          \
                    float sc = qk_sh[jr * 9 + g] + s2[r];                       \
                    sc = fminf(5.f, fmaxf(-5.f, sc));                           \
                    const float p  = __expf(sc);                                \
                    const float mm = mi * msk_sh[jr];                           \
                    const float s1 = p * mm;               /* mask^1 -> denom */\
                    dnm[ct] += s1;                                              \
                    const float vv = vrow[r * CC];                              \
                    acc[ct] = fmaf(s1 * mm, vv + eE[r], acc[ct]); /* mask^2 */  \
                }                                                               \
            }                                                                   \
        }                                                                       \
    }

    // ITER(TT, load-target regs = tile TT+2, store-source regs = tile TT+1)
#define ITER(TT, L0, L1, S0, S1)                                                \
    {                                                                           \
        if ((TT) < 6) { L0 = esrc[((TT)+2)*512]; L1 = esrc[((TT)+2)*512+1]; }   \
        COMPUTE_TILE(TT);                                                       \
        if ((TT) < 7) { STORE_TILE(((TT)+1) % 3, S0, S1); __syncthreads(); }    \
    }

    ITER(0, x0, x1, y0, y1)   // load t2->x, compute t0, store t1 from y
    ITER(1, y0, y1, x0, x1)   // load t3->y, compute t1, store t2 from x
    ITER(2, x0, x1, y0, y1)
    ITER(3, y0, y1, x0, x1)
    ITER(4, x0, x1, y0, y1)
    ITER(5, y0, y1, x0, x1)
    ITER(6, x0, x1, y0, y1)   // no load, compute t6, store t7 from y
    ITER(7, y0, y1, x0, x1)   // no load, compute t7, no store/sync

#undef ITER
#undef COMPUTE_TILE
#undef STORE_TILE

    // reduce over quad groups (lanes l, l^16, l^32, l^48 share a column)
    #pragma unroll
    for (int ct = 0; ct < 2; ++ct) {
        float a = acc[ct], d = dnm[ct];
        a += __shfl_xor(a, 16); a += __shfl_xor(a, 32);
        d += __shfl_xor(d, 16); d += __shfl_xor(d, 32);
        acc[ct] = a; dnm[ct] = d;
    }
    if (lane < 32) {
        const int ct = lane >> 4;
        out[(size_t)row * CC + wave * 32 + lane] = acc[ct] / fmaxf(dnm[ct], 1e-6f);
    }
}

extern "C" void kernel_launch(void* const* d_in, const int* in_sizes, int n_in,
                              void* d_out, int out_size, void* d_ws, size_t ws_size,
                              hipStream_t stream)
{
    const float* h    = (const float*)d_in[0];
    const float* e    = (const float*)d_in[1];
    const float* mask = (const float*)d_in[2];
    const float* WQ   = (const float*)d_in[3];
    const float* WK   = (const float*)d_in[4];
    const float* WV   = (const float*)d_in[5];
    const float* WE   = (const float*)d_in[6];
    const float* WE2  = (const float*)d_in[7];

    unsigned short* wfrag = (unsigned short*)d_ws;          // 32 KB
    float* Qw = (float*)((char*)d_ws + 32768);              // B*N*C f32 each
    float* Kw = Qw + BB * NN * CC;
    float* Vw = Kw + BB * NN * CC;                          // total ~1.53 MB

    prep_kernel<<<264, 256, 0, stream>>>(h, WQ, WK, WV, WE, WE2,
                                         Qw, Kw, Vw, wfrag);
    attn_kernel<<<BB*NN, 256, 0, stream>>>(e, mask, wfrag, Qw, Kw, Vw,
                                           (float*)d_out);
}

// Round 5
// 137.061 us; speedup vs baseline: 1.8583x; 1.0773x over previous
//
#include <hip/hip_runtime.h>

// (B,N,DIN,DE,NH,DK) = (4,256,128,64,8,16). Inputs f32, output f32.
#define BB   4
#define NN   256
#define DIN  128
#define DE   64
#define NH   8
#define DK   16
#define CC   128   // NH*DK

typedef __attribute__((ext_vector_type(8))) short short8;   // 8 bf16 = 4 VGPRs
typedef __attribute__((ext_vector_type(4))) float f32x4;

// f32 -> bf16 bits, round-to-nearest-even (round-4-verified numerics)
__device__ __forceinline__ unsigned short f2bfu(float f) {
    union { float f; unsigned int i; } v; v.f = f;
    unsigned int x = v.i;
    x += 0x7FFFu + ((x >> 16) & 1u);
    return (unsigned short)(x >> 16);
}

// ---------------------------------------------------------------------------
// prep: blocks [0,256) do QKV (4 rows per block, verified structure);
//       blocks [256,264) do the one-time WE/WE2 f32->bf16 B-fragment prep.
// wfrag[((m*8+g)*2+ks)*64 + lane] = short8 { W[ks*32+q4*8+ii][g*16+l15] }
// ---------------------------------------------------------------------------
__global__ __launch_bounds__(256) void prep_kernel(
    const float* __restrict__ h, const float* __restrict__ WQ,
    const float* __restrict__ WK, const float* __restrict__ WV,
    const float* __restrict__ WE, const float* __restrict__ WE2,
    float* __restrict__ Qw, float* __restrict__ Kw, float* __restrict__ Vw,
    unsigned short* __restrict__ wfrag)
{
    __shared__ float hsh[4 * DIN];       // 2 KB
    __shared__ float psum[4 * 1536];     // 24 KB
    const int t = threadIdx.x;

    if (blockIdx.x >= 256) {
        // ---- W-frag prep (8 blocks x 256 thr = 2048 threads) ----
        const int tid  = (blockIdx.x - 256) * 256 + t;
        const int m    = tid >> 10;
        const int g    = (tid >> 7) & 7;
        const int ks   = (tid >> 6) & 1;
        const int lane = tid & 63;
        const int q4 = lane >> 4, l15 = lane & 15;
        const float* W = m ? WE2 : WE;
        union { uint4 u; unsigned short s[8]; } pk;
        #pragma unroll
        for (int ii = 0; ii < 8; ++ii) {
            const int d = ks * 32 + q4 * 8 + ii;
            pk.s[ii] = f2bfu(W[d * CC + g * 16 + l15]);
        }
        ((uint4*)wfrag)[tid] = pk.u;
        return;
    }

    // ---- QKV: 4 rows per block ----
    const int r0 = blockIdx.x * 4;
    hsh[t]       = h[(size_t)r0 * DIN + t];
    hsh[256 + t] = h[(size_t)r0 * DIN + 256 + t];
    __syncthreads();

    const int cp  = t & 63;              // channel pair: c = 2cp, 2cp+1
    const int qtr = t >> 6;              // d in [qtr*32, qtr*32+32)
    float aq[4][2], ak[4][2], av[4][2];
    #pragma unroll
    for (int r = 0; r < 4; ++r) {
        aq[r][0]=aq[r][1]=ak[r][0]=ak[r][1]=av[r][0]=av[r][1]=0.f;
    }
    #pragma unroll 4
    for (int dd = 0; dd < 32; ++dd) {
        const int d = qtr * 32 + dd;
        const float2 fq = ((const float2*)WQ)[d * 64 + cp];
        const float2 fk = ((const float2*)WK)[d * 64 + cp];
        const float2 fv = ((const float2*)WV)[d * 64 + cp];
        #pragma unroll
        for (int r = 0; r < 4; ++r) {
            const float hd = hsh[r * DIN + d];
            aq[r][0] = fmaf(hd, fq.x, aq[r][0]); aq[r][1] = fmaf(hd, fq.y, aq[r][1]);
            ak[r][0] = fmaf(hd, fk.x, ak[r][0]); ak[r][1] = fmaf(hd, fk.y, ak[r][1]);
            av[r][0] = fmaf(hd, fv.x, av[r][0]); av[r][1] = fmaf(hd, fv.y, av[r][1]);
        }
    }
    float* pq = psum + qtr * 1536;
    #pragma unroll
    for (int r = 0; r < 4; ++r) {
        pq[r*384       + 2*cp] = aq[r][0]; pq[r*384       + 2*cp+1] = aq[r][1];
        pq[r*384 + 128 + 2*cp] = ak[r][0]; pq[r*384 + 128 + 2*cp+1] = ak[r][1];
        pq[r*384 + 256 + 2*cp] = av[r][0]; pq[r*384 + 256 + 2*cp+1] = av[r][1];
    }
    __syncthreads();
    #pragma unroll
    for (int k = 0; k < 6; ++k) {
        const int o = k * 256 + t;               // 0..1535
        float v = psum[o] + psum[1536 + o] + psum[3072 + o] + psum[4608 + o];
        const int r   = o / 384;
        const int mc  = o - r * 384;
        const int mat = mc >> 7;
        const int c   = mc & 127;
        const size_t idx = (size_t)(r0 + r) * CC + c;
        if      (mat == 0) Qw[idx] = v;
        else if (mat == 1) Kw[idx] = v * 0.25f;  // DK^-0.5
        else               Vw[idx] = v;
    }
}

// ---------------------------------------------------------------------------
// Fused attention. One block (4 waves) per (b,i). Monolithic e-stage
// (round-0 structure, proven fastest). ROUND-3 POST-MORTEM: the old inner
// loop paid a serial ~400-cycle LDS+VMEM latency per (s,ct,r) combo because
// the 84-VGPR allocation kept qk_sh/msk/vv loads just-in-time. Waves were
// ~93% stalled (VALUBusy 22% / 3-wave occupancy). This version BATCHES all
// per-slab memory ops into registers first (vv[2][4], qk[2][4], mm[4]),
// then runs MFMAs + pure-VALU tail -> one overlapped latency per slab
// instead of 16 serial ones. +~24 VGPR, still < the (256,3) ~170 cap.
//
// MFMA 16x16x32 bf16 layouts (HW-verified):
//   A: lane holds A[m=lane&15][k=(lane>>4)*8+ii]
//   B: lane holds B[k=(lane>>4)*8+ii][n=lane&15]
//   C/D: col=lane&15, row=(lane>>4)*4+reg
// ---------------------------------------------------------------------------
__global__ __launch_bounds__(256, 3) void attn_kernel(
    const float* __restrict__ e, const float* __restrict__ maskp,
    const unsigned short* __restrict__ wfrag,
    const float* __restrict__ Qw, const float* __restrict__ Kw,
    const float* __restrict__ Vw, float* __restrict__ out)
{
    __shared__ __align__(16) unsigned short esh[NN * DE];  // 32 KB, swizzled
    __shared__ float qk_sh[NN * 9];                        // 9 KB, pad 9
    __shared__ float msk_sh[NN];
    __shared__ float qrow_sh[CC];

    const int row  = blockIdx.x;
    const int b    = row >> 8, i = row & 255;
    const int t    = threadIdx.x;
    const int wave = t >> 6, lane = t & 63;
    const int q4   = lane >> 4;
    const int l15  = lane & 15;

    // --- stage e[b,i,:,:] f32 -> bf16, XOR-swizzled 16B chunks ---
    {
        const float4* src = (const float4*)(e + (size_t)row * NN * DE);
        uint4* dst = (uint4*)esh;
        #pragma unroll
        for (int r = 0; r < 8; ++r) {
            const int cidx = r * 256 + t;        // chunk 0..2047
            const int j = cidx >> 3, ch = cidx & 7;
            const float4 f0 = src[2 * cidx];
            const float4 f1 = src[2 * cidx + 1];
            union { uint4 u; unsigned short s[8]; } pk;
            pk.s[0]=f2bfu(f0.x); pk.s[1]=f2bfu(f0.y); pk.s[2]=f2bfu(f0.z); pk.s[3]=f2bfu(f0.w);
            pk.s[4]=f2bfu(f1.x); pk.s[5]=f2bfu(f1.y); pk.s[6]=f2bfu(f1.z); pk.s[7]=f2bfu(f1.w);
            dst[j * 8 + (ch ^ (j & 7))] = pk.u;
        }
    }
    if (t < CC) qrow_sh[t] = Qw[(size_t)row * CC + t];
    msk_sh[t] = maskp[b * NN + t];

    // --- B-fragments straight from global (L2-hot), no barrier needed ---
    short8 bfrag[2][2][2];
    {
        const uint4* wf = (const uint4*)wfrag;
        #pragma unroll
        for (int m = 0; m < 2; ++m)
        #pragma unroll
        for (int ct = 0; ct < 2; ++ct) {
            const int g = wave * 2 + ct;
            #pragma unroll
            for (int ks = 0; ks < 2; ++ks) {
                union { uint4 u; short8 s8; } cv;
                cv.u = wf[((m * 8 + g) * 2 + ks) * 64 + lane];
                bfrag[m][ct][ks] = cv.s8;
            }
        }
    }
    __syncthreads();

    // --- qk[j,h], full f32 (thread t = row j) ---
    {
        const float4* kr = (const float4*)(Kw + (size_t)(b * NN + t) * CC);
        #pragma unroll
        for (int hh = 0; hh < NH; ++hh) {
            float s = 0.f;
            #pragma unroll
            for (int p = 0; p < 4; ++p) {
                const float4 kv = kr[hh * 4 + p];
                const int qb = hh * 16 + p * 4;
                s += kv.x * qrow_sh[qb]     + kv.y * qrow_sh[qb + 1]
                   + kv.z * qrow_sh[qb + 2] + kv.w * qrow_sh[qb + 3];
            }
            qk_sh[t * 9 + hh] = s;
        }
    }
    __syncthreads();

    const float mi = msk_sh[i];
    float acc[2] = {0.f, 0.f}, dnm[2] = {0.f, 0.f};
    const short8* ep = (const short8*)esh;
    const int g0 = wave * 2, g1 = wave * 2 + 1;

    #pragma unroll 2
    for (int s = 0; s < 16; ++s) {
        const int ja = s * 16 + l15;
        const short8 a0 = ep[ja * 8 + ((q4    ) ^ (ja & 7))];  // d 0..31
        const short8 a1 = ep[ja * 8 + ((q4 + 4) ^ (ja & 7))];  // d 32..63

        // ---- batched V loads (8 VMEM issued together, one latency) ----
        float vv[2][4];
        {
            const float* vr0 = Vw + (size_t)(b*NN + s*16 + q4*4) * CC + g0*16 + l15;
            const float* vr1 = Vw + (size_t)(b*NN + s*16 + q4*4) * CC + g1*16 + l15;
            #pragma unroll
            for (int r = 0; r < 4; ++r) { vv[0][r] = vr0[r * CC]; vv[1][r] = vr1[r * CC]; }
        }
        // ---- batched qk + mask (12 LDS reads issued together) ----
        float qk0[4], qk1[4], mm[4], mm2[4];
        #pragma unroll
        for (int r = 0; r < 4; ++r) {
            const int jr = s * 16 + q4 * 4 + r;
            qk0[r] = qk_sh[jr * 9 + g0];
            qk1[r] = qk_sh[jr * 9 + g1];
            const float m = mi * msk_sh[jr];
            mm[r] = m; mm2[r] = m * m;
        }

        f32x4 s2a = {0.f,0.f,0.f,0.f}, eEa = {0.f,0.f,0.f,0.f};
        f32x4 s2b = {0.f,0.f,0.f,0.f}, eEb = {0.f,0.f,0.f,0.f};
        s2a = __builtin_amdgcn_mfma_f32_16x16x32_bf16(a0, bfrag[1][0][0], s2a, 0,0,0);
        s2a = __builtin_amdgcn_mfma_f32_16x16x32_bf16(a1, bfrag[1][0][1], s2a, 0,0,0);
        eEa = __builtin_amdgcn_mfma_f32_16x16x32_bf16(a0, bfrag[0][0][0], eEa, 0,0,0);
        eEa = __builtin_amdgcn_mfma_f32_16x16x32_bf16(a1, bfrag[0][0][1], eEa, 0,0,0);
        s2b = __builtin_amdgcn_mfma_f32_16x16x32_bf16(a0, bfrag[1][1][0], s2b, 0,0,0);
        s2b = __builtin_amdgcn_mfma_f32_16x16x32_bf16(a1, bfrag[1][1][1], s2b, 0,0,0);
        eEb = __builtin_amdgcn_mfma_f32_16x16x32_bf16(a0, bfrag[0][1][0], eEb, 0,0,0);
        eEb = __builtin_amdgcn_mfma_f32_16x16x32_bf16(a1, bfrag[0][1][1], eEb, 0,0,0);

        // ---- pure-VALU tail (no memory ops in the dependence chain) ----
        #pragma unroll
        for (int r = 0; r < 4; ++r) {
            float sa = qk0[r] + s2a[r];
            sa = fminf(5.f, fmaxf(-5.f, sa));
            const float pa = __expf(sa);
            dnm[0] += pa * mm[r];
            acc[0] = fmaf(pa * mm2[r], vv[0][r] + eEa[r], acc[0]);

            float sb = qk1[r] + s2b[r];
            sb = fminf(5.f, fmaxf(-5.f, sb));
            const float pb = __expf(sb);
            dnm[1] += pb * mm[r];
            acc[1] = fmaf(pb * mm2[r], vv[1][r] + eEb[r], acc[1]);
        }
    }

    // reduce over quad groups (lanes l, l^16, l^32, l^48 share a column)
    #pragma unroll
    for (int ct = 0; ct < 2; ++ct) {
        float a = acc[ct], d = dnm[ct];
        a += __shfl_xor(a, 16); a += __shfl_xor(a, 32);
        d += __shfl_xor(d, 16); d += __shfl_xor(d, 32);
        acc[ct] = a; dnm[ct] = d;
    }
    if (lane < 32) {
        const int ct = lane >> 4;
        out[(size_t)row * CC + wave * 32 + lane] = acc[ct] / fmaxf(dnm[ct], 1e-6f);
    }
}

extern "C" void kernel_launch(void* const* d_in, const int* in_sizes, int n_in,
                              void* d_out, int out_size, void* d_ws, size_t ws_size,
                              hipStream_t stream)
{
    const float* h    = (const float*)d_in[0];
    const float* e    = (const float*)d_in[1];
    const float* mask = (const float*)d_in[2];
    const float* WQ   = (const float*)d_in[3];
    const float* WK   = (const float*)d_in[4];
    const float* WV   = (const float*)d_in[5];
    const float* WE   = (const float*)d_in[6];
    const float* WE2  = (const float*)d_in[7];

    unsigned short* wfrag = (unsigned short*)d_ws;          // 32 KB
    float* Qw = (float*)((char*)d_ws + 32768);              // B*N*C f32 each
    float* Kw = Qw + BB * NN * CC;
    float* Vw = Kw + BB * NN * CC;                          // total ~1.53 MB

    prep_kernel<<<264, 256, 0, stream>>>(h, WQ, WK, WV, WE, WE2,
                                         Qw, Kw, Vw, wfrag);
    attn_kernel<<<BB*NN, 256, 0, stream>>>(e, mask, wfrag, Qw, Kw, Vw,
                                           (float*)d_out);
}